// Round 2
// baseline (204.901 us; speedup 1.0000x reference)
//
#include <hip/hip_runtime.h>
#include <stdint.h>

constexpr int NN = 50000;
constexpr int NE = 800000;
constexpr int H  = 128;

__device__ __forceinline__ uint32_t f32key(float f) {
  uint32_t b = __float_as_uint(f);
  return (b & 0x80000000u) ? ~b : (b | 0x80000000u);
}

// K1: logits[i] = x[i].W_le + b_le ; lkey[i] = pack(logit_i, i) (self-loop);
//     cnt[i] = 0 ; out row i = 0 (scatter accumulator init).
__global__ void k_logits(const float* __restrict__ x,
                         const float* __restrict__ Wle, const float* __restrict__ ble,
                         float* __restrict__ logits, unsigned long long* __restrict__ lkey,
                         float* __restrict__ cnt, float* __restrict__ out) {
  int wave = (blockIdx.x * blockDim.x + threadIdx.x) >> 6;
  int lane = threadIdx.x & 63;
  if (wave >= NN) return;
  const float* xr = x + (size_t)wave * H;
  float v = xr[lane] * Wle[lane] + xr[lane + 64] * Wle[lane + 64];
  for (int off = 32; off > 0; off >>= 1) v += __shfl_xor(v, off, 64);
  // zero the output row (used as the scatter-sum accumulator)
  *(float2*)(out + (size_t)wave * H + lane * 2) = make_float2(0.f, 0.f);
  if (lane == 0) {
    float lg = v + ble[0];
    logits[wave] = lg;
    lkey[wave] = ((unsigned long long)f32key(lg) << 32) | (unsigned long long)(uint32_t)wave;
    cnt[wave] = 0.f;
  }
}

// K2: per-edge leader election via 64-bit atomicMax of (logit_key, src)
__global__ void k_elect(const int* __restrict__ esrc, const int* __restrict__ edst,
                        const float* __restrict__ logits, unsigned long long* __restrict__ lkey) {
  int e = blockIdx.x * blockDim.x + threadIdx.x;
  if (e >= NE) return;
  int s = esrc[e];
  int d = edst[e];
  unsigned long long key =
      ((unsigned long long)f32key(logits[s]) << 32) | (unsigned long long)(uint32_t)s;
  atomicMax(&lkey[d], key);
}

// K3: masked scatter-add of x[src] onto out[dst], only where dst is a self-leader.
// 32 threads per edge, one float4 each.
__global__ void k_scatter(const int* __restrict__ esrc, const int* __restrict__ edst,
                          const unsigned long long* __restrict__ lkey,
                          const float* __restrict__ x,
                          float* __restrict__ out, float* __restrict__ cnt) {
  int g = blockIdx.x * blockDim.x + threadIdx.x;
  int e = g >> 5, q = g & 31;
  if (e >= NE) return;
  int d = edst[e];
  if ((uint32_t)lkey[d] != (uint32_t)d) return;  // dst not its own leader: report never read
  int s = esrc[e];
  const float4 xv = *(const float4*)(x + (size_t)s * H + q * 4);
  float* o = out + (size_t)d * H + q * 4;
  atomicAdd(o + 0, xv.x);
  atomicAdd(o + 1, xv.y);
  atomicAdd(o + 2, xv.z);
  atomicAdd(o + 3, xv.w);
  if (q == 0) atomicAdd(&cnt[d], 1.0f);
}

// K4: MLP for self-leader rows only; in-place on d_out row b (read into LDS first).
__global__ void __launch_bounds__(128) k_mlp(
    const unsigned long long* __restrict__ lkey,
    const float* __restrict__ cnt,
    const float* __restrict__ W1, const float* __restrict__ b1,
    const float* __restrict__ W2, const float* __restrict__ b2,
    float* __restrict__ out) {
  int b = blockIdx.x;
  if ((uint32_t)lkey[b] != (uint32_t)b) return;  // uniform branch
  __shared__ float sm[H];
  int j = threadIdx.x;
  float rc = 1.0f / fmaxf(cnt[b], 1.0f);
  sm[j] = out[(size_t)b * H + j] * rc;  // nmean
  __syncthreads();
  float acc = b1[j];
#pragma unroll 8
  for (int k = 0; k < H; ++k) acc = fmaf(sm[k], W1[k * H + j], acc);
  float hg = 0.5f * acc * (1.0f + erff(acc * 0.70710678118654752f));  // exact GELU
  __syncthreads();
  sm[j] = hg;
  __syncthreads();
  float acc2 = b2[j];
#pragma unroll 8
  for (int k = 0; k < H; ++k) acc2 = fmaf(sm[k], W2[k * H + j], acc2);
  out[(size_t)b * H + j] = acc2;
}

// K5: every non-self-leader row i copies its leader's report (or zero).
__global__ void k_out(const unsigned long long* __restrict__ lkey,
                      float* __restrict__ out) {
  int g = blockIdx.x * blockDim.x + threadIdx.x;
  int i = g >> 5, q = g & 31;
  if (i >= NN) return;
  int L = (int)(uint32_t)lkey[i];
  if (L == i) return;  // self-leader rows already written by k_mlp
  float4 v = make_float4(0.f, 0.f, 0.f, 0.f);
  if ((uint32_t)lkey[L] == (uint32_t)L)
    v = *(const float4*)(out + (size_t)L * H + q * 4);
  *(float4*)(out + (size_t)i * H + q * 4) = v;
}

extern "C" void kernel_launch(void* const* d_in, const int* in_sizes, int n_in,
                              void* d_out, int out_size, void* d_ws, size_t ws_size,
                              hipStream_t stream) {
  (void)in_sizes; (void)n_in; (void)out_size; (void)ws_size;
  const float* x   = (const float*)d_in[0];
  const int* ei    = (const int*)d_in[1];   // [2][NE] int32 (harness converts integer inputs)
  const float* Wle = (const float*)d_in[2];
  const float* ble = (const float*)d_in[3];
  const float* W1  = (const float*)d_in[4];
  const float* b1  = (const float*)d_in[5];
  const float* W2  = (const float*)d_in[6];
  const float* b2  = (const float*)d_in[7];
  float* out       = (float*)d_out;

  char* ws = (char*)d_ws;
  unsigned long long* lkey = (unsigned long long*)ws;  // NN*8  = 400000 B
  float* cnt    = (float*)(ws + 400000);               // NN*4  = 200000 B
  float* logits = (float*)(ws + 600000);               // NN*4  = 200000 B

  const int* esrc = ei;
  const int* edst = ei + NE;

  k_logits<<<(NN + 3) / 4, 256, 0, stream>>>(x, Wle, ble, logits, lkey, cnt, out);
  k_elect<<<(NE + 255) / 256, 256, 0, stream>>>(esrc, edst, logits, lkey);
  {
    long long tot = (long long)NE * 32;
    k_scatter<<<(int)((tot + 255) / 256), 256, 0, stream>>>(esrc, edst, lkey, x, out, cnt);
  }
  k_mlp<<<NN, 128, 0, stream>>>(lkey, cnt, W1, b1, W2, b2, out);
  {
    long long tot = (long long)NN * 32;
    k_out<<<(int)((tot + 255) / 256), 256, 0, stream>>>(lkey, out);
  }
}

// Round 3
// 111.474 us; speedup vs baseline: 1.8381x; 1.8381x over previous
//
#include <hip/hip_runtime.h>
#include <stdint.h>

constexpr int NN  = 50000;
constexpr int NE  = 800000;
constexpr int H   = 128;
constexpr int CAP = 48;   // bucket capacity; P(indeg>=48 | Poisson(16)) ~ e^-70, guarded anyway
constexpr int RB  = 8;    // rows per MLP block

__device__ __forceinline__ uint32_t f32key(float f) {
  uint32_t b = __float_as_uint(f);
  return (b & 0x80000000u) ? ~b : (b | 0x80000000u);
}

// K1: logits + self-loop election key init + cnt/nsl zeroing.
__global__ void k_logits(const float* __restrict__ x,
                         const float* __restrict__ Wle, const float* __restrict__ ble,
                         float* __restrict__ logits, unsigned long long* __restrict__ lkey,
                         int* __restrict__ cnt, int* __restrict__ nsl) {
  int gid  = blockIdx.x * blockDim.x + threadIdx.x;
  int wave = gid >> 6, lane = threadIdx.x & 63;
  if (gid == 0) *nsl = 0;
  if (wave >= NN) return;
  const float* xr = x + (size_t)wave * H;
  float v = xr[lane] * Wle[lane] + xr[lane + 64] * Wle[lane + 64];
  for (int off = 32; off > 0; off >>= 1) v += __shfl_xor(v, off, 64);
  if (lane == 0) {
    float lg = v + ble[0];
    logits[wave] = lg;
    lkey[wave] = ((unsigned long long)f32key(lg) << 32) | (unsigned long long)(uint32_t)wave;
    cnt[wave] = 0;
  }
}

// K2: leader election; monotone-safe read filter before atomicMax.
__global__ void k_elect(const int* __restrict__ esrc, const int* __restrict__ edst,
                        const float* __restrict__ logits, unsigned long long* __restrict__ lkey) {
  int e = blockIdx.x * blockDim.x + threadIdx.x;
  if (e >= NE) return;
  int s = esrc[e], d = edst[e];
  unsigned long long key =
      ((unsigned long long)f32key(logits[s]) << 32) | (unsigned long long)(uint32_t)s;
  if (lkey[d] >= key) return;  // stale value only underestimates -> safe skip
  atomicMax(&lkey[d], key);
}

// K3: build self-leader list + bucket passing edges by destination.
__global__ void k_place(const int* __restrict__ esrc, const int* __restrict__ edst,
                        const unsigned long long* __restrict__ lkey,
                        int* __restrict__ cnt, int* __restrict__ bucket,
                        int* __restrict__ slist, int* __restrict__ nsl) {
  int t = blockIdx.x * blockDim.x + threadIdx.x;
  if (t < NN) {
    if ((uint32_t)lkey[t] == (uint32_t)t) {
      int p = atomicAdd(nsl, 1);
      slist[p] = t;
    }
  }
  if (t >= NE) return;
  int d = edst[t];
  if ((uint32_t)lkey[d] != (uint32_t)d) return;  // dst's report never read
  int slot = atomicAdd(&cnt[d], 1);
  if (slot < CAP) bucket[(size_t)d * CAP + slot] = esrc[t];
}

// K4: per self-leader, atomic-free neighbor-sum -> nmean written into out row.
__global__ void __launch_bounds__(128) k_gather(
    const int* __restrict__ slist, const int* __restrict__ nsl,
    const int* __restrict__ cnt, const int* __restrict__ bucket,
    const float* __restrict__ x, float* __restrict__ out) {
  int b = blockIdx.x;
  if (b >= *nsl) return;
  int node = slist[b];
  int c = cnt[node];
  int cc = min(c, CAP);
  __shared__ int ss[CAP];
  int j = threadIdx.x;
  if (j < cc) ss[j] = bucket[(size_t)node * CAP + j];
  __syncthreads();
  double acc = 0.0;  // order-insensitive accumulation (bucket order is race-dependent)
  for (int e = 0; e < cc; ++e) acc += (double)x[(size_t)ss[e] * H + j];
  float rc = 1.0f / (float)max(c, 1);
  out[(size_t)node * H + j] = (float)acc * rc;
}

// K5: MLP on self-leader rows, RB rows per block (amortize weight reads), in-place on out.
__global__ void __launch_bounds__(128) k_mlp8(
    const int* __restrict__ slist, const int* __restrict__ nsl,
    const float* __restrict__ W1, const float* __restrict__ b1,
    const float* __restrict__ W2, const float* __restrict__ b2,
    float* __restrict__ out) {
  int base = blockIdx.x * RB;
  int ns = *nsl;
  if (base >= ns) return;
  int v = min(RB, ns - base);
  __shared__ float sm[RB][H];
  __shared__ int nodes[RB];
  int j = threadIdx.x;
  if (j < RB) nodes[j] = (j < v) ? slist[base + j] : 0;
  __syncthreads();
#pragma unroll
  for (int r = 0; r < RB; ++r)
    if (r < v) sm[r][j] = out[(size_t)nodes[r] * H + j];
  __syncthreads();
  float acc[RB];
#pragma unroll
  for (int r = 0; r < RB; ++r) acc[r] = b1[j];
  for (int k = 0; k < H; ++k) {
    float w = W1[k * H + j];
#pragma unroll
    for (int r = 0; r < RB; ++r) acc[r] = fmaf(sm[r][k], w, acc[r]);
  }
  __syncthreads();
#pragma unroll
  for (int r = 0; r < RB; ++r)
    sm[r][j] = 0.5f * acc[r] * (1.0f + erff(acc[r] * 0.70710678118654752f));
  __syncthreads();
#pragma unroll
  for (int r = 0; r < RB; ++r) acc[r] = b2[j];
  for (int k = 0; k < H; ++k) {
    float w = W2[k * H + j];
#pragma unroll
    for (int r = 0; r < RB; ++r) acc[r] = fmaf(sm[r][k], w, acc[r]);
  }
#pragma unroll
  for (int r = 0; r < RB; ++r)
    if (r < v) out[(size_t)nodes[r] * H + j] = acc[r];
}

// K6: non-self-leader rows copy their leader's report (or zero).
__global__ void k_out(const unsigned long long* __restrict__ lkey,
                      float* __restrict__ out) {
  int g = blockIdx.x * blockDim.x + threadIdx.x;
  int i = g >> 5, q = g & 31;
  if (i >= NN) return;
  int L = (int)(uint32_t)lkey[i];
  if (L == i) return;  // self-leader rows already final
  float4 v = make_float4(0.f, 0.f, 0.f, 0.f);
  if ((uint32_t)lkey[L] == (uint32_t)L)
    v = *(const float4*)(out + (size_t)L * H + q * 4);
  *(float4*)(out + (size_t)i * H + q * 4) = v;
}

extern "C" void kernel_launch(void* const* d_in, const int* in_sizes, int n_in,
                              void* d_out, int out_size, void* d_ws, size_t ws_size,
                              hipStream_t stream) {
  (void)in_sizes; (void)n_in; (void)out_size; (void)ws_size;
  const float* x   = (const float*)d_in[0];
  const int* ei    = (const int*)d_in[1];   // [2][NE] int32
  const float* Wle = (const float*)d_in[2];
  const float* ble = (const float*)d_in[3];
  const float* W1  = (const float*)d_in[4];
  const float* b1  = (const float*)d_in[5];
  const float* W2  = (const float*)d_in[6];
  const float* b2  = (const float*)d_in[7];
  float* out       = (float*)d_out;

  char* ws = (char*)d_ws;
  unsigned long long* lkey = (unsigned long long*)ws;        // 400000 B
  float* logits = (float*)(ws + 400000);                     // 200000 B
  int*   cnt    = (int*)  (ws + 600000);                     // 200000 B
  int*   slist  = (int*)  (ws + 800000);                     // 200000 B
  int*   nsl    = (int*)  (ws + 1000000);                    // 256 B
  int*   bucket = (int*)  (ws + 1000256);                    // NN*CAP*4 = 9.6 MB

  const int* esrc = ei;
  const int* edst = ei + NE;

  k_logits<<<(NN * 64 + 255) / 256, 256, 0, stream>>>(x, Wle, ble, logits, lkey, cnt, nsl);
  k_elect<<<(NE + 255) / 256, 256, 0, stream>>>(esrc, edst, logits, lkey);
  k_place<<<(NE + 255) / 256, 256, 0, stream>>>(esrc, edst, lkey, cnt, bucket, slist, nsl);
  k_gather<<<NN, 128, 0, stream>>>(slist, nsl, cnt, bucket, x, out);
  k_mlp8<<<(NN + RB - 1) / RB, 128, 0, stream>>>(slist, nsl, W1, b1, W2, b2, out);
  k_out<<<(NN * 32 + 255) / 256, 256, 0, stream>>>(lkey, out);
}